// Round 6
// baseline (674.859 us; speedup 1.0000x reference)
//
#include <hip/hip_runtime.h>
#include <hip/hip_bf16.h>

typedef __attribute__((ext_vector_type(8))) short short8;
typedef __attribute__((ext_vector_type(4))) short short4v;
typedef __attribute__((ext_vector_type(4))) float float4v;

#define NB 8
#define NH 12
#define NN 1024
#define ND 64
#define NC 768

#define RAWBAR() do { \
  asm volatile("s_waitcnt lgkmcnt(0)" ::: "memory"); \
  __builtin_amdgcn_s_barrier(); \
} while (0)

// XOR swizzle for Sb: spread 32B-stride columns across banks. Pure function of address.
#define SWZ(byt) ((byt) ^ (((((byt) >> 5) ^ ((byt) >> 12)) & 7) << 4))

__device__ __forceinline__ short f2bf(float f) {
  __hip_bfloat16 h = __float2bfloat16(f);
  union { __hip_bfloat16 h; short s; } u; u.h = h; return u.s;
}
__device__ __forceinline__ unsigned pk2(float a, float b) {
  unsigned ua = (unsigned short)f2bf(a);
  unsigned ub = (unsigned short)f2bf(b);
  return ua | (ub << 16);
}

// ---------------- GEMM: MODE 0 = QKV (A fp32, scatter to Q/K bf16 + V^T),
// ----------------       MODE 1 = proj (A bf16, +bias, fp32 out) ----------------
template<int MODE>
__global__ __launch_bounds__(256, 2)
void gemm_kernel(const void* __restrict__ Ap, const float* __restrict__ Bw,
                 const float* __restrict__ bias,
                 __hip_bfloat16* __restrict__ Qo, __hip_bfloat16* __restrict__ Ko,
                 __hip_bfloat16* __restrict__ VTo, float* __restrict__ Out)
{
  __shared__ short As[128 * 40];
  __shared__ short Bs[128 * 40];
  const int tid = threadIdx.x;
  const int w = tid >> 6, lane = tid & 63, lr = lane & 15, lg = lane >> 4;
  const int wr = w >> 1, wc = w & 1;
  const int n0 = blockIdx.x * 128, m0 = blockIdx.y * 128;

  float4v acc[4][4];
  #pragma unroll
  for (int i = 0; i < 4; i++)
    #pragma unroll
    for (int j = 0; j < 4; j++)
      acc[i][j] = (float4v){0.f, 0.f, 0.f, 0.f};

  for (int kt = 0; kt < 768; kt += 32) {
    if (MODE == 0) {
      const float* A = (const float*)Ap;
      #pragma unroll
      for (int i2 = 0; i2 < 4; i2++) {
        int c = tid + 256 * i2;
        int row = c >> 3, c4 = c & 7;
        float4v v = *(const float4v*)(A + (size_t)(m0 + row) * 768 + kt + c4 * 4);
        short4v s = { f2bf(v[0]), f2bf(v[1]), f2bf(v[2]), f2bf(v[3]) };
        *(short4v*)(&As[row * 40 + c4 * 4]) = s;
      }
    } else {
      const __hip_bfloat16* A = (const __hip_bfloat16*)Ap;
      #pragma unroll
      for (int i2 = 0; i2 < 2; i2++) {
        int c = tid + 256 * i2;
        int row = c >> 2, c8 = c & 3;
        *(short8*)(&As[row * 40 + c8 * 8]) =
            *(const short8*)(A + (size_t)(m0 + row) * 768 + kt + c8 * 8);
      }
    }
    #pragma unroll
    for (int i2 = 0; i2 < 4; i2++) {
      int c = tid + 256 * i2;
      int row = c >> 3, c4 = c & 7;
      float4v v = *(const float4v*)(Bw + (size_t)(n0 + row) * 768 + kt + c4 * 4);
      short4v s = { f2bf(v[0]), f2bf(v[1]), f2bf(v[2]), f2bf(v[3]) };
      *(short4v*)(&Bs[row * 40 + c4 * 4]) = s;
    }
    __syncthreads();

    short8 af[4], bfr[4];
    #pragma unroll
    for (int i = 0; i < 4; i++)
      af[i] = *(const short8*)(&As[(wr * 64 + i * 16 + lr) * 40 + lg * 8]);
    #pragma unroll
    for (int j = 0; j < 4; j++)
      bfr[j] = *(const short8*)(&Bs[(wc * 64 + j * 16 + lr) * 40 + lg * 8]);
    #pragma unroll
    for (int i = 0; i < 4; i++)
      #pragma unroll
      for (int j = 0; j < 4; j++)
        acc[i][j] = __builtin_amdgcn_mfma_f32_16x16x32_bf16(af[i], bfr[j], acc[i][j], 0, 0, 0);
    __syncthreads();
  }

  #pragma unroll
  for (int i = 0; i < 4; i++) {
    #pragma unroll
    for (int j = 0; j < 4; j++) {
      #pragma unroll
      for (int r = 0; r < 4; r++) {
        float val = acc[i][j][r];
        int mg_ = m0 + wr * 64 + i * 16 + lg * 4 + r;
        int ng_ = n0 + wc * 64 + j * 16 + lr;
        if (MODE == 0) {
          int s = ng_ / 768;
          int rem = ng_ - s * 768;
          int h = rem >> 6, d = rem & 63;
          int b = mg_ >> 10, n = mg_ & 1023;
          if (s == 0)
            Qo[(((size_t)b * NH + h) * NN + n) * ND + d] = __float2bfloat16(val * 0.125f);
          else if (s == 1)
            Ko[(((size_t)b * NH + h) * NN + n) * ND + d] = __float2bfloat16(val);
          else  // V stored transposed: VT[b][h][d][m]
            VTo[(((size_t)b * NH + h) * ND + d) * NN + n] = __float2bfloat16(val);
        } else {
          Out[(size_t)mg_ * NC + ng_] = val + bias[ng_];
        }
      }
    }
  }
}

// ---------------- fused talking-heads attention, 8-wave fine-split ----------------
// grid = 512 blocks x 512 threads (8 waves). b = blk&7 (XCD-local), n0 = (blk>>3)*16.
// Work units per t: QK 24 = (12h x 2 m-half) -> 3/wave; PV 24 = (12o2 x 2 d-pair) -> 3/wave;
// conv chunks 32 -> 4/wave. Sb: [32 chunk][16 col][16 k] shorts, XOR-swizzled, +128B zero tail.
__global__ __launch_bounds__(512, 4)
void attn_kernel(const __hip_bfloat16* __restrict__ Qg, const __hip_bfloat16* __restrict__ Kg,
                 const __hip_bfloat16* __restrict__ VTg,
                 const float* __restrict__ convl, const float* __restrict__ convw,
                 __hip_bfloat16* __restrict__ AOut)
{
  __shared__ short Sb[8256];       // 16384 B data + 128 B zero tail
  __shared__ short pm[16 * 648];   // [o2(16 rows, 12 used)][n(16)][m(40)] bf16
  __shared__ short lwA[512];       // lw A-frag [o(16)][h(32)], zero-padded
  __shared__ short wwT[512];       // ww B-frag [o2(16)][o(32)], zero-padded

  char* Sbb = (char*)Sb;
  const int tid = threadIdx.x;
  const int w = tid >> 6, lane = tid & 63, lr = lane & 15, lg = lane >> 4;
  const int b = blockIdx.x & 7;          // XCD swizzle
  const int n0 = (blockIdx.x >> 3) * 16;
  const int u0 = w * 3;                  // units u0..u0+2
  const int h0 = u0 >> 1;                // first of the wave's 2 heads
  const float4v zf = (float4v){0.f, 0.f, 0.f, 0.f};

  for (int i = tid; i < 512; i += 512) {
    int r = i >> 5, k = i & 31;
    bool v = (r < 12) && (k < 12);
    lwA[i] = v ? f2bf(convl[r * 12 + k]) : (short)0;
    wwT[i] = v ? f2bf(convw[r * 12 + k]) : (short)0;
  }
  // zero Sb pad k=12..15 of every col (8 B each) + 128 B tail
  {
    int chunk = tid >> 4, col = tid & 15;
    *(int*)(Sbb + SWZ(chunk * 512 + col * 32 + 24)) = 0;
    *(int*)(Sbb + SWZ(chunk * 512 + col * 32 + 28)) = 0;
    if (tid < 32) *(int*)(Sbb + 16384 + tid * 4) = 0;
  }

  // Q A-fragments for the wave's 2 heads
  short8 qf[2][2];
  #pragma unroll
  for (int hi = 0; hi < 2; hi++)
    #pragma unroll
    for (int ks = 0; ks < 2; ks++)
      qf[hi][ks] = *(const short8*)(Qg +
          (((size_t)b * NH + h0 + hi) * NN + n0 + lr) * ND + ks * 32 + lg * 8);

  // K B-frag prefetch: unit u -> (h=u>>1, j=u&1), 6 x short8 = 24 VGPR
  short8 kreg[3][2];
  auto loadK = [&](int t) {
    #pragma unroll
    for (int uu = 0; uu < 3; uu++) {
      int u = u0 + uu, h = u >> 1, j = u & 1;
      const size_t kbase = (((size_t)b * NH + h) * NN + t * 32 + j * 16 + lr) * ND;
      #pragma unroll
      for (int ks = 0; ks < 2; ks++)
        kreg[uu][ks] = *(const short8*)(Kg + kbase + ks * 32 + lg * 8);
    }
  };

  loadK(0);
  RAWBAR();
  const short8 lwf = *(const short8*)(&lwA[lr * 32 + lg * 8]);  // A[row=o][k=h]
  const short8 wwf = *(const short8*)(&wwT[lr * 32 + lg * 8]);  // B[k=o][col=o2]

  // ================= PASS 1: L[o][n] = sum_m exp(S') =================
  float Lacc[4][2];
  #pragma unroll
  for (int r = 0; r < 4; r++) { Lacc[r][0] = 0.f; Lacc[r][1] = 0.f; }

  for (int t = 0; t < 32; t++) {
    __builtin_amdgcn_s_setprio(1);
    #pragma unroll
    for (int uu = 0; uu < 3; uu++) {
      int u = u0 + uu, h = u >> 1, j = u & 1, hi = h - h0;
      float4v a = __builtin_amdgcn_mfma_f32_16x16x32_bf16(qf[hi][0], kreg[uu][0], zf, 0, 0, 0);
      a = __builtin_amdgcn_mfma_f32_16x16x32_bf16(qf[hi][1], kreg[uu][1], a, 0, 0, 0);
      #pragma unroll
      for (int r = 0; r < 4; r++)
        *(short*)(Sbb + SWZ((((lg * 4 + r) * 2 + j) * 512) + lr * 32 + h * 2)) = f2bf(a[r]);
    }
    __builtin_amdgcn_s_setprio(0);
    loadK(t < 31 ? t + 1 : 0);   // stays in flight across barriers
    RAWBAR();
    #pragma unroll
    for (int cc = 0; cc < 4; cc++) {
      const int c = w * 4 + cc;
      short8 sb = *(const short8*)(Sbb + SWZ(c * 512 + lr * 32 + lg * 16));
      float4v d = __builtin_amdgcn_mfma_f32_16x16x32_bf16(lwf, sb, zf, 0, 0, 0);
      #pragma unroll
      for (int r = 0; r < 4; r++)
        Lacc[r][cc >> 1] += __expf(d[r]);
    }
    RAWBAR();
  }
  float logLreg[4][2];
  #pragma unroll
  for (int r = 0; r < 4; r++)
    #pragma unroll
    for (int nn = 0; nn < 2; nn++) {
      float v = Lacc[r][nn];
      v += __shfl_xor(v, 1);
      v += __shfl_xor(v, 2);
      v += __shfl_xor(v, 4);
      v += __shfl_xor(v, 8);
      logLreg[r][nn] = __logf(v);
    }

  // ================= PASS 2: P=exp(S'-logL) -> conv_w -> PV =================
  float4v oacc[3][2];
  #pragma unroll
  for (int uu = 0; uu < 3; uu++) { oacc[uu][0] = zf; oacc[uu][1] = zf; }

  for (int t = 0; t <= 32; t++) {
    // ---- Phase A: pf reads | vt loads | QK(t)->Sb | loadK(t+1) | PV(t-1) ----
    short8 pf[3];
    short8 vt[3][2];
    if (t > 0) {
      const int m0v = (t - 1) * 32;
      #pragma unroll
      for (int uu = 0; uu < 3; uu++) {
        int u = u0 + uu, o2v = u >> 1, jdp = u & 1;
        pf[uu] = *(const short8*)(&pm[o2v * 648 + lr * 40 + lg * 8]);
        const size_t vbase = ((size_t)b * NH + o2v) * ND * NN;
        #pragma unroll
        for (int q = 0; q < 2; q++)
          vt[uu][q] = *(const short8*)(VTg + vbase +
              (size_t)((jdp * 2 + q) * 16 + lr) * NN + m0v + lg * 8);
      }
    }
    __builtin_amdgcn_s_setprio(1);
    if (t < 32) {
      #pragma unroll
      for (int uu = 0; uu < 3; uu++) {
        int u = u0 + uu, h = u >> 1, j = u & 1, hi = h - h0;
        float4v a = __builtin_amdgcn_mfma_f32_16x16x32_bf16(qf[hi][0], kreg[uu][0], zf, 0, 0, 0);
        a = __builtin_amdgcn_mfma_f32_16x16x32_bf16(qf[hi][1], kreg[uu][1], a, 0, 0, 0);
        #pragma unroll
        for (int r = 0; r < 4; r++)
          *(short*)(Sbb + SWZ((((lg * 4 + r) * 2 + j) * 512) + lr * 32 + h * 2)) = f2bf(a[r]);
      }
      if (t < 31) loadK(t + 1);
    }
    if (t > 0) {
      #pragma unroll
      for (int uu = 0; uu < 3; uu++)
        #pragma unroll
        for (int q = 0; q < 2; q++)
          oacc[uu][q] = __builtin_amdgcn_mfma_f32_16x16x32_bf16(vt[uu][q], pf[uu], oacc[uu][q], 0, 0, 0);
    }
    __builtin_amdgcn_s_setprio(0);
    RAWBAR();
    // ---- Phase B: conv_l -> exp -> P(in place) -> conv_w -> pm ----
    if (t < 32) {
      #pragma unroll
      for (int cc = 0; cc < 4; cc++) {
        const int c = w * 4 + cc;
        short8 sb = *(const short8*)(Sbb + SWZ(c * 512 + lr * 32 + lg * 16));
        float4v d = __builtin_amdgcn_mfma_f32_16x16x32_bf16(lwf, sb, zf, 0, 0, 0);
        float p0 = __expf(d[0] - logLreg[0][cc >> 1]);
        float p1 = __expf(d[1] - logLreg[1][cc >> 1]);
        float p2 = __expf(d[2] - logLreg[2][cc >> 1]);
        float p3 = __expf(d[3] - logLreg[3][cc >> 1]);
        // P[o=lg*4+r][pos=lr] -> Sb[c][col=lr][k=o], two b32 (k = lg*4 .. lg*4+3)
        *(unsigned*)(Sbb + SWZ(c * 512 + lr * 32 + lg * 8)) = pk2(p0, p1);
        *(unsigned*)(Sbb + SWZ(c * 512 + lr * 32 + lg * 8 + 4)) = pk2(p2, p3);
      }
      asm volatile("s_waitcnt lgkmcnt(0)" ::: "memory");
      __builtin_amdgcn_sched_barrier(0);
      #pragma unroll
      for (int cc = 0; cc < 4; cc++) {
        const int c = w * 4 + cc;
        short8 pb = *(const short8*)(Sbb + SWZ(c * 512 + lr * 32 + lg * 16));
        float4v d = __builtin_amdgcn_mfma_f32_16x16x32_bf16(pb, wwf, zf, 0, 0, 0);
        // lane: o2 = lr, pos = lg*4+r, n = c>>1, m = (c&1)*16 + pos
        unsigned* dst = (unsigned*)(&pm[lr * 648 + (c >> 1) * 40 + (c & 1) * 16 + lg * 4]);
        dst[0] = pk2(d[0], d[1]);
        dst[1] = pk2(d[2], d[3]);
      }
    }
    RAWBAR();
  }

  // epilogue: unit (o2, jdp): lane holds n = n0+lr, d = jdp*32 + q*16 + lg*4 + r
  #pragma unroll
  for (int uu = 0; uu < 3; uu++) {
    int u = u0 + uu, o2v = u >> 1, jdp = u & 1;
    #pragma unroll
    for (int q = 0; q < 2; q++) {
      size_t base = ((size_t)b * NN + n0 + lr) * NC + o2v * 64 + jdp * 32 + q * 16 + lg * 4;
      unsigned* dst = (unsigned*)(&AOut[base]);
      dst[0] = pk2(oacc[uu][q][0], oacc[uu][q][1]);
      dst[1] = pk2(oacc[uu][q][2], oacc[uu][q][3]);
    }
  }
}

extern "C" void kernel_launch(void* const* d_in, const int* in_sizes, int n_in,
                              void* d_out, int out_size, void* d_ws, size_t ws_size,
                              hipStream_t stream) {
  const float* x      = (const float*)d_in[0];
  const float* w_qkv  = (const float*)d_in[1];
  const float* w_proj = (const float*)d_in[2];
  const float* b_proj = (const float*)d_in[3];
  const float* conv_l = (const float*)d_in[4];
  const float* conv_w = (const float*)d_in[5];
  float* out = (float*)d_out;

  const size_t NE = (size_t)NB * NH * NN * ND;
  __hip_bfloat16* Qb = (__hip_bfloat16*)d_ws;
  __hip_bfloat16* Kb = Qb + NE;
  __hip_bfloat16* VT = Kb + NE;
  __hip_bfloat16* AO = VT + NE;   // [B*N][C] bf16

  gemm_kernel<0><<<dim3(18, 64), 256, 0, stream>>>(x, w_qkv, nullptr, Qb, Kb, VT, nullptr);
  attn_kernel<<<dim3(512), 512, 0, stream>>>(Qb, Kb, VT, conv_l, conv_w, AO);
  gemm_kernel<1><<<dim3(6, 64), 256, 0, stream>>>(AO, w_proj, b_proj, nullptr, nullptr, nullptr, out);
}

// Round 7
// 442.395 us; speedup vs baseline: 1.5255x; 1.5255x over previous
//
#include <hip/hip_runtime.h>
#include <hip/hip_bf16.h>

typedef __attribute__((ext_vector_type(8))) short short8;
typedef __attribute__((ext_vector_type(4))) short short4v;
typedef __attribute__((ext_vector_type(4))) float float4v;

#define NB 8
#define NH 12
#define NN 1024
#define ND 64
#define NC 768

#define RAWBAR() do { \
  asm volatile("s_waitcnt lgkmcnt(0)" ::: "memory"); \
  __builtin_amdgcn_s_barrier(); \
} while (0)

// Sb swizzle: flip k-half (byte bit4) by col bit2 (byte bit7).
// Sb access patterns become <=2-way bank aliased (2-way is free).
#define SWZ(byt) ((byt) ^ ((((byt) >> 7) & 1) << 4))

__device__ __forceinline__ short f2bf(float f) {
  __hip_bfloat16 h = __float2bfloat16(f);
  union { __hip_bfloat16 h; short s; } u; u.h = h; return u.s;
}
__device__ __forceinline__ unsigned pk2(float a, float b) {
  unsigned ua = (unsigned short)f2bf(a);
  unsigned ub = (unsigned short)f2bf(b);
  return ua | (ub << 16);
}

// ---------------- GEMM: MODE 0 = QKV (A fp32, scatter to Q/K bf16 + V^T),
// ----------------       MODE 1 = proj (A bf16, +bias, fp32 out) ----------------
template<int MODE>
__global__ __launch_bounds__(256, 2)
void gemm_kernel(const void* __restrict__ Ap, const float* __restrict__ Bw,
                 const float* __restrict__ bias,
                 __hip_bfloat16* __restrict__ Qo, __hip_bfloat16* __restrict__ Ko,
                 __hip_bfloat16* __restrict__ VTo, float* __restrict__ Out)
{
  __shared__ short As[128 * 40];
  __shared__ short Bs[128 * 40];
  const int tid = threadIdx.x;
  const int w = tid >> 6, lane = tid & 63, lr = lane & 15, lg = lane >> 4;
  const int wr = w >> 1, wc = w & 1;
  const int n0 = blockIdx.x * 128, m0 = blockIdx.y * 128;

  float4v acc[4][4];
  #pragma unroll
  for (int i = 0; i < 4; i++)
    #pragma unroll
    for (int j = 0; j < 4; j++)
      acc[i][j] = (float4v){0.f, 0.f, 0.f, 0.f};

  for (int kt = 0; kt < 768; kt += 32) {
    if (MODE == 0) {
      const float* A = (const float*)Ap;
      #pragma unroll
      for (int i2 = 0; i2 < 4; i2++) {
        int c = tid + 256 * i2;
        int row = c >> 3, c4 = c & 7;
        float4v v = *(const float4v*)(A + (size_t)(m0 + row) * 768 + kt + c4 * 4);
        short4v s = { f2bf(v[0]), f2bf(v[1]), f2bf(v[2]), f2bf(v[3]) };
        *(short4v*)(&As[row * 40 + c4 * 4]) = s;
      }
    } else {
      const __hip_bfloat16* A = (const __hip_bfloat16*)Ap;
      #pragma unroll
      for (int i2 = 0; i2 < 2; i2++) {
        int c = tid + 256 * i2;
        int row = c >> 2, c8 = c & 3;
        *(short8*)(&As[row * 40 + c8 * 8]) =
            *(const short8*)(A + (size_t)(m0 + row) * 768 + kt + c8 * 8);
      }
    }
    #pragma unroll
    for (int i2 = 0; i2 < 4; i2++) {
      int c = tid + 256 * i2;
      int row = c >> 3, c4 = c & 7;
      float4v v = *(const float4v*)(Bw + (size_t)(n0 + row) * 768 + kt + c4 * 4);
      short4v s = { f2bf(v[0]), f2bf(v[1]), f2bf(v[2]), f2bf(v[3]) };
      *(short4v*)(&Bs[row * 40 + c4 * 4]) = s;
    }
    __syncthreads();

    short8 af[4], bfr[4];
    #pragma unroll
    for (int i = 0; i < 4; i++)
      af[i] = *(const short8*)(&As[(wr * 64 + i * 16 + lr) * 40 + lg * 8]);
    #pragma unroll
    for (int j = 0; j < 4; j++)
      bfr[j] = *(const short8*)(&Bs[(wc * 64 + j * 16 + lr) * 40 + lg * 8]);
    #pragma unroll
    for (int i = 0; i < 4; i++)
      #pragma unroll
      for (int j = 0; j < 4; j++)
        acc[i][j] = __builtin_amdgcn_mfma_f32_16x16x32_bf16(af[i], bfr[j], acc[i][j], 0, 0, 0);
    __syncthreads();
  }

  #pragma unroll
  for (int i = 0; i < 4; i++) {
    #pragma unroll
    for (int j = 0; j < 4; j++) {
      #pragma unroll
      for (int r = 0; r < 4; r++) {
        float val = acc[i][j][r];
        int mg_ = m0 + wr * 64 + i * 16 + lg * 4 + r;
        int ng_ = n0 + wc * 64 + j * 16 + lr;
        if (MODE == 0) {
          int s = ng_ / 768;
          int rem = ng_ - s * 768;
          int h = rem >> 6, d = rem & 63;
          int b = mg_ >> 10, n = mg_ & 1023;
          if (s == 0)
            Qo[(((size_t)b * NH + h) * NN + n) * ND + d] = __float2bfloat16(val * 0.125f);
          else if (s == 1)
            Ko[(((size_t)b * NH + h) * NN + n) * ND + d] = __float2bfloat16(val);
          else  // V stored transposed: VT[b][h][d][m]
            VTo[(((size_t)b * NH + h) * ND + d) * NN + n] = __float2bfloat16(val);
        } else {
          Out[(size_t)mg_ * NC + ng_] = val + bias[ng_];
        }
      }
    }
  }
}

// ---------------- fused talking-heads attention, 8-wave fine-split ----------------
// grid = 512 blocks x 512 threads (8 waves), launch_bounds(512,2) -> 2 blocks/CU,
// 4 waves/SIMD, 128-VGPR budget. b = blk&7 (XCD-local), n0 = (blk>>3)*16.
// Units per t: QK 24 = (12h x 2 m-half) -> 3/wave; PV 24 = (12o2 x 2 d-pair) -> 3/wave;
// conv chunks 32 -> 4/wave. Sb: [32 chunk][16 col][16 k] shorts, SWZ bank fix.
__global__ __launch_bounds__(512, 2)
void attn_kernel(const __hip_bfloat16* __restrict__ Qg, const __hip_bfloat16* __restrict__ Kg,
                 const __hip_bfloat16* __restrict__ VTg,
                 const float* __restrict__ convl, const float* __restrict__ convw,
                 __hip_bfloat16* __restrict__ AOut)
{
  __shared__ short Sb[8192];       // 16384 B
  __shared__ short pm[16 * 648];   // [o2(16 rows, 12 used)][n(16)][m(40)] bf16
  __shared__ short lwA[512];       // lw A-frag [o(16)][h(32)], zero-padded
  __shared__ short wwT[512];       // ww B-frag [o2(16)][o(32)], zero-padded

  char* Sbb = (char*)Sb;
  const int tid = threadIdx.x;
  const int w = tid >> 6, lane = tid & 63, lr = lane & 15, lg = lane >> 4;
  const int b = blockIdx.x & 7;          // XCD swizzle
  const int n0 = (blockIdx.x >> 3) * 16;
  const int u0 = w * 3;                  // units u0..u0+2
  const int h0 = u0 >> 1;                // first of the wave's 2 heads
  const float4v zf = (float4v){0.f, 0.f, 0.f, 0.f};

  for (int i = tid; i < 512; i += 512) {
    int r = i >> 5, k = i & 31;
    bool v = (r < 12) && (k < 12);
    lwA[i] = v ? f2bf(convl[r * 12 + k]) : (short)0;
    wwT[i] = v ? f2bf(convw[r * 12 + k]) : (short)0;
  }
  // zero Sb pad k=12..15 of every col (8 B each)
  {
    int chunk = tid >> 4, col = tid & 15;
    *(int*)(Sbb + SWZ(chunk * 512 + col * 32 + 24)) = 0;
    *(int*)(Sbb + SWZ(chunk * 512 + col * 32 + 28)) = 0;
  }

  // Q A-fragments for the wave's 2 heads
  short8 qf[2][2];
  #pragma unroll
  for (int hi = 0; hi < 2; hi++)
    #pragma unroll
    for (int ks = 0; ks < 2; ks++)
      qf[hi][ks] = *(const short8*)(Qg +
          (((size_t)b * NH + h0 + hi) * NN + n0 + lr) * ND + ks * 32 + lg * 8);

  // K B-frag prefetch: unit u -> (h=u>>1, j=u&1), 6 x short8 = 24 VGPR
  short8 kreg[3][2];
  auto loadK = [&](int t) {
    #pragma unroll
    for (int uu = 0; uu < 3; uu++) {
      int u = u0 + uu, h = u >> 1, j = u & 1;
      const size_t kbase = (((size_t)b * NH + h) * NN + t * 32 + j * 16 + lr) * ND;
      #pragma unroll
      for (int ks = 0; ks < 2; ks++)
        kreg[uu][ks] = *(const short8*)(Kg + kbase + ks * 32 + lg * 8);
    }
  };

  loadK(0);
  RAWBAR();
  const short8 lwf = *(const short8*)(&lwA[lr * 32 + lg * 8]);  // A[row=o][k=h]
  const short8 wwf = *(const short8*)(&wwT[lr * 32 + lg * 8]);  // B[k=o][col=o2]

  // ================= PASS 1: L[o][n] = sum_m exp(S') =================
  float Lacc[4][2];
  #pragma unroll
  for (int r = 0; r < 4; r++) { Lacc[r][0] = 0.f; Lacc[r][1] = 0.f; }

  for (int t = 0; t < 32; t++) {
    __builtin_amdgcn_s_setprio(1);
    #pragma unroll
    for (int uu = 0; uu < 3; uu++) {
      int u = u0 + uu, h = u >> 1, j = u & 1, hi = h - h0;
      float4v a = __builtin_amdgcn_mfma_f32_16x16x32_bf16(qf[hi][0], kreg[uu][0], zf, 0, 0, 0);
      a = __builtin_amdgcn_mfma_f32_16x16x32_bf16(qf[hi][1], kreg[uu][1], a, 0, 0, 0);
      #pragma unroll
      for (int r = 0; r < 4; r++)
        *(short*)(Sbb + SWZ((((lg * 4 + r) * 2 + j) * 512) + lr * 32 + h * 2)) = f2bf(a[r]);
    }
    __builtin_amdgcn_s_setprio(0);
    loadK(t < 31 ? t + 1 : 0);   // stays in flight across barriers
    RAWBAR();
    #pragma unroll
    for (int cc = 0; cc < 4; cc++) {
      const int c = w * 4 + cc;
      short8 sb = *(const short8*)(Sbb + SWZ(c * 512 + lr * 32 + lg * 16));
      float4v d = __builtin_amdgcn_mfma_f32_16x16x32_bf16(lwf, sb, zf, 0, 0, 0);
      #pragma unroll
      for (int r = 0; r < 4; r++)
        Lacc[r][cc >> 1] += __expf(d[r]);
    }
    RAWBAR();
  }
  float logLreg[4][2];
  #pragma unroll
  for (int r = 0; r < 4; r++)
    #pragma unroll
    for (int nn = 0; nn < 2; nn++) {
      float v = Lacc[r][nn];
      v += __shfl_xor(v, 1);
      v += __shfl_xor(v, 2);
      v += __shfl_xor(v, 4);
      v += __shfl_xor(v, 8);
      logLreg[r][nn] = __logf(v);
    }

  // ================= PASS 2: P=exp(S'-logL) -> conv_w -> PV =================
  float4v oacc[3][2];
  #pragma unroll
  for (int uu = 0; uu < 3; uu++) { oacc[uu][0] = zf; oacc[uu][1] = zf; }

  for (int t = 0; t <= 32; t++) {
    // ---- Phase A: pf reads | vt loads | QK(t)->Sb | loadK(t+1) | PV(t-1) ----
    short8 pf[3];
    short8 vt[3][2];
    if (t > 0) {
      const int m0v = (t - 1) * 32;
      #pragma unroll
      for (int uu = 0; uu < 3; uu++) {
        int u = u0 + uu, o2v = u >> 1, jdp = u & 1;
        pf[uu] = *(const short8*)(&pm[o2v * 648 + lr * 40 + lg * 8]);
        const size_t vbase = ((size_t)b * NH + o2v) * ND * NN;
        #pragma unroll
        for (int q = 0; q < 2; q++)
          vt[uu][q] = *(const short8*)(VTg + vbase +
              (size_t)((jdp * 2 + q) * 16 + lr) * NN + m0v + lg * 8);
      }
    }
    __builtin_amdgcn_s_setprio(1);
    if (t < 32) {
      #pragma unroll
      for (int uu = 0; uu < 3; uu++) {
        int u = u0 + uu, h = u >> 1, j = u & 1, hi = h - h0;
        float4v a = __builtin_amdgcn_mfma_f32_16x16x32_bf16(qf[hi][0], kreg[uu][0], zf, 0, 0, 0);
        a = __builtin_amdgcn_mfma_f32_16x16x32_bf16(qf[hi][1], kreg[uu][1], a, 0, 0, 0);
        #pragma unroll
        for (int r = 0; r < 4; r++)
          *(short*)(Sbb + SWZ((((lg * 4 + r) * 2 + j) * 512) + lr * 32 + h * 2)) = f2bf(a[r]);
      }
      if (t < 31) loadK(t + 1);
    }
    if (t > 0) {
      #pragma unroll
      for (int uu = 0; uu < 3; uu++)
        #pragma unroll
        for (int q = 0; q < 2; q++)
          oacc[uu][q] = __builtin_amdgcn_mfma_f32_16x16x32_bf16(vt[uu][q], pf[uu], oacc[uu][q], 0, 0, 0);
    }
    __builtin_amdgcn_s_setprio(0);
    RAWBAR();
    // ---- Phase B: conv_l -> exp -> P(in place) -> conv_w -> pm ----
    if (t < 32) {
      #pragma unroll
      for (int cc = 0; cc < 4; cc++) {
        const int c = w * 4 + cc;
        short8 sb = *(const short8*)(Sbb + SWZ(c * 512 + lr * 32 + lg * 16));
        float4v d = __builtin_amdgcn_mfma_f32_16x16x32_bf16(lwf, sb, zf, 0, 0, 0);
        float p0 = __expf(d[0] - logLreg[0][cc >> 1]);
        float p1 = __expf(d[1] - logLreg[1][cc >> 1]);
        float p2 = __expf(d[2] - logLreg[2][cc >> 1]);
        float p3 = __expf(d[3] - logLreg[3][cc >> 1]);
        // P[o=lg*4+r][pos=lr] -> Sb[c][col=lr][k=o], two b32 (k = lg*4 .. lg*4+3)
        *(unsigned*)(Sbb + SWZ(c * 512 + lr * 32 + lg * 8)) = pk2(p0, p1);
        *(unsigned*)(Sbb + SWZ(c * 512 + lr * 32 + lg * 8 + 4)) = pk2(p2, p3);
      }
      asm volatile("s_waitcnt lgkmcnt(0)" ::: "memory");
      __builtin_amdgcn_sched_barrier(0);
      #pragma unroll
      for (int cc = 0; cc < 4; cc++) {
        const int c = w * 4 + cc;
        short8 pb = *(const short8*)(Sbb + SWZ(c * 512 + lr * 32 + lg * 16));
        float4v d = __builtin_amdgcn_mfma_f32_16x16x32_bf16(pb, wwf, zf, 0, 0, 0);
        // lane: o2 = lr, pos = lg*4+r, n = c>>1, m = (c&1)*16 + pos
        unsigned* dst = (unsigned*)(&pm[lr * 648 + (c >> 1) * 40 + (c & 1) * 16 + lg * 4]);
        dst[0] = pk2(d[0], d[1]);
        dst[1] = pk2(d[2], d[3]);
      }
    }
    RAWBAR();
  }

  // epilogue: unit (o2, jdp): lane holds n = n0+lr, d = jdp*32 + q*16 + lg*4 + r
  #pragma unroll
  for (int uu = 0; uu < 3; uu++) {
    int u = u0 + uu, o2v = u >> 1, jdp = u & 1;
    #pragma unroll
    for (int q = 0; q < 2; q++) {
      size_t base = ((size_t)b * NN + n0 + lr) * NC + o2v * 64 + jdp * 32 + q * 16 + lg * 4;
      unsigned* dst = (unsigned*)(&AOut[base]);
      dst[0] = pk2(oacc[uu][q][0], oacc[uu][q][1]);
      dst[1] = pk2(oacc[uu][q][2], oacc[uu][q][3]);
    }
  }
}

extern "C" void kernel_launch(void* const* d_in, const int* in_sizes, int n_in,
                              void* d_out, int out_size, void* d_ws, size_t ws_size,
                              hipStream_t stream) {
  const float* x      = (const float*)d_in[0];
  const float* w_qkv  = (const float*)d_in[1];
  const float* w_proj = (const float*)d_in[2];
  const float* b_proj = (const float*)d_in[3];
  const float* conv_l = (const float*)d_in[4];
  const float* conv_w = (const float*)d_in[5];
  float* out = (float*)d_out;

  const size_t NE = (size_t)NB * NH * NN * ND;
  __hip_bfloat16* Qb = (__hip_bfloat16*)d_ws;
  __hip_bfloat16* Kb = Qb + NE;
  __hip_bfloat16* VT = Kb + NE;
  __hip_bfloat16* AO = VT + NE;   // [B*N][C] bf16

  gemm_kernel<0><<<dim3(18, 64), 256, 0, stream>>>(x, w_qkv, nullptr, Qb, Kb, VT, nullptr);
  attn_kernel<<<dim3(512), 512, 0, stream>>>(Qb, Kb, VT, conv_l, conv_w, AO);
  gemm_kernel<1><<<dim3(6, 64), 256, 0, stream>>>(AO, w_proj, b_proj, nullptr, nullptr, nullptr, out);
}

// Round 8
// 376.997 us; speedup vs baseline: 1.7901x; 1.1735x over previous
//
#include <hip/hip_runtime.h>
#include <hip/hip_bf16.h>

typedef __attribute__((ext_vector_type(8))) short short8;
typedef __attribute__((ext_vector_type(4))) short short4v;
typedef __attribute__((ext_vector_type(4))) float float4v;

#define NB 8
#define NH 12
#define NN 1024
#define ND 64
#define NC 768

#define RAWBAR() do { \
  asm volatile("s_waitcnt lgkmcnt(0)" ::: "memory"); \
  __builtin_amdgcn_s_barrier(); \
} while (0)

__device__ __forceinline__ short f2bf(float f) {
  __hip_bfloat16 h = __float2bfloat16(f);
  union { __hip_bfloat16 h; short s; } u; u.h = h; return u.s;
}
__device__ __forceinline__ unsigned pk2(float a, float b) {
  unsigned ua = (unsigned short)f2bf(a);
  unsigned ub = (unsigned short)f2bf(b);
  return ua | (ub << 16);
}

// ---------------- GEMM: MODE 0 = QKV (A fp32, scatter to Q/K bf16 + V^T),
// ----------------       MODE 1 = proj (A bf16, +bias, fp32 out) ----------------
template<int MODE>
__global__ __launch_bounds__(256, 2)
void gemm_kernel(const void* __restrict__ Ap, const float* __restrict__ Bw,
                 const float* __restrict__ bias,
                 __hip_bfloat16* __restrict__ Qo, __hip_bfloat16* __restrict__ Ko,
                 __hip_bfloat16* __restrict__ VTo, float* __restrict__ Out)
{
  __shared__ short As[128 * 40];
  __shared__ short Bs[128 * 40];
  const int tid = threadIdx.x;
  const int w = tid >> 6, lane = tid & 63, lr = lane & 15, lg = lane >> 4;
  const int wr = w >> 1, wc = w & 1;
  const int n0 = blockIdx.x * 128, m0 = blockIdx.y * 128;

  float4v acc[4][4];
  #pragma unroll
  for (int i = 0; i < 4; i++)
    #pragma unroll
    for (int j = 0; j < 4; j++)
      acc[i][j] = (float4v){0.f, 0.f, 0.f, 0.f};

  for (int kt = 0; kt < 768; kt += 32) {
    if (MODE == 0) {
      const float* A = (const float*)Ap;
      #pragma unroll
      for (int i2 = 0; i2 < 4; i2++) {
        int c = tid + 256 * i2;
        int row = c >> 3, c4 = c & 7;
        float4v v = *(const float4v*)(A + (size_t)(m0 + row) * 768 + kt + c4 * 4);
        short4v s = { f2bf(v[0]), f2bf(v[1]), f2bf(v[2]), f2bf(v[3]) };
        *(short4v*)(&As[row * 40 + c4 * 4]) = s;
      }
    } else {
      const __hip_bfloat16* A = (const __hip_bfloat16*)Ap;
      #pragma unroll
      for (int i2 = 0; i2 < 2; i2++) {
        int c = tid + 256 * i2;
        int row = c >> 2, c8 = c & 3;
        *(short8*)(&As[row * 40 + c8 * 8]) =
            *(const short8*)(A + (size_t)(m0 + row) * 768 + kt + c8 * 8);
      }
    }
    #pragma unroll
    for (int i2 = 0; i2 < 4; i2++) {
      int c = tid + 256 * i2;
      int row = c >> 3, c4 = c & 7;
      float4v v = *(const float4v*)(Bw + (size_t)(n0 + row) * 768 + kt + c4 * 4);
      short4v s = { f2bf(v[0]), f2bf(v[1]), f2bf(v[2]), f2bf(v[3]) };
      *(short4v*)(&Bs[row * 40 + c4 * 4]) = s;
    }
    __syncthreads();

    short8 af[4], bfr[4];
    #pragma unroll
    for (int i = 0; i < 4; i++)
      af[i] = *(const short8*)(&As[(wr * 64 + i * 16 + lr) * 40 + lg * 8]);
    #pragma unroll
    for (int j = 0; j < 4; j++)
      bfr[j] = *(const short8*)(&Bs[(wc * 64 + j * 16 + lr) * 40 + lg * 8]);
    #pragma unroll
    for (int i = 0; i < 4; i++)
      #pragma unroll
      for (int j = 0; j < 4; j++)
        acc[i][j] = __builtin_amdgcn_mfma_f32_16x16x32_bf16(af[i], bfr[j], acc[i][j], 0, 0, 0);
    __syncthreads();
  }

  #pragma unroll
  for (int i = 0; i < 4; i++) {
    #pragma unroll
    for (int j = 0; j < 4; j++) {
      #pragma unroll
      for (int r = 0; r < 4; r++) {
        float val = acc[i][j][r];
        int mg_ = m0 + wr * 64 + i * 16 + lg * 4 + r;
        int ng_ = n0 + wc * 64 + j * 16 + lr;
        if (MODE == 0) {
          int s = ng_ / 768;
          int rem = ng_ - s * 768;
          int h = rem >> 6, d = rem & 63;
          int b = mg_ >> 10, n = mg_ & 1023;
          if (s == 0)
            Qo[(((size_t)b * NH + h) * NN + n) * ND + d] = __float2bfloat16(val * 0.125f);
          else if (s == 1)
            Ko[(((size_t)b * NH + h) * NN + n) * ND + d] = __float2bfloat16(val);
          else  // V stored transposed: VT[b][h][d][m]
            VTo[(((size_t)b * NH + h) * ND + d) * NN + n] = __float2bfloat16(val);
        } else {
          Out[(size_t)mg_ * NC + ng_] = val + bias[ng_];
        }
      }
    }
  }
}

// ---------------- fused talking-heads attention, 1-barrier-per-tile ----------------
// grid = 512 blocks x 256 threads (4 waves), 2 blocks/CU. b = blk&7 (XCD-local).
// Segment t: QK(t)->Sb[t&1] || conv_l/exp[/conv_w](t-1) from Sb[(t-1)&1] || PV(t-2).
// Sb: [2][32 chunk][16 col][18 k] shorts (bank step 9). pm: [2][16 o2][584] shorts.
__global__ __launch_bounds__(256, 2)
void attn_kernel(const __hip_bfloat16* __restrict__ Qg, const __hip_bfloat16* __restrict__ Kg,
                 const __hip_bfloat16* __restrict__ VTg,
                 const float* __restrict__ convl, const float* __restrict__ convw,
                 __hip_bfloat16* __restrict__ AOut)
{
  __shared__ short Sb[18432];      // 2 bufs x 32 x 16 x 18 = 36864 B
  __shared__ short pm[18688];      // 2 bufs x 16 x 584     = 37376 B
  __shared__ short lwA[512];       // lw A-frag [o(16)][h(32)], zero-padded
  __shared__ short wwT[512];       // ww B-frag [k=o(16)][o2(32)], zero-padded

  const int tid = threadIdx.x;
  const int w = tid >> 6, lane = tid & 63, lr = lane & 15, lg = lane >> 4;
  const int b = blockIdx.x & 7;          // XCD swizzle
  const int n0 = (blockIdx.x >> 3) * 16;
  const float4v zf = (float4v){0.f, 0.f, 0.f, 0.f};

  for (int i = tid; i < 512; i += 256) {
    int r = i >> 5, k = i & 31;
    bool v = (r < 12) && (k < 12);
    lwA[i] = v ? f2bf(convl[r * 12 + k]) : (short)0;
    wwT[i] = v ? f2bf(convw[r * 12 + k]) : (short)0;
  }
  // zero Sb k-pad [12..17] of every (buf,chunk,col)
  for (int i = tid; i < 1024; i += 256) {
    unsigned* p = (unsigned*)(&Sb[i * 18 + 12]);
    p[0] = 0; p[1] = 0; p[2] = 0;
  }

  // Q A-fragments: wave w owns heads 3w..3w+2
  short8 qf[3][2];
  #pragma unroll
  for (int hh = 0; hh < 3; hh++)
    #pragma unroll
    for (int ks = 0; ks < 2; ks++)
      qf[hh][ks] = *(const short8*)(Qg +
          (((size_t)b * NH + w * 3 + hh) * NN + n0 + lr) * ND + ks * 32 + lg * 8);

  // K B-frag prefetch registers (12 x short8 = 48 VGPR)
  short8 kreg[3][2][2];
  auto loadK = [&](int t) {
    #pragma unroll
    for (int hh = 0; hh < 3; hh++) {
      const size_t kbase = (((size_t)b * NH + w * 3 + hh) * NN + t * 32) * ND;
      #pragma unroll
      for (int j = 0; j < 2; j++)
        #pragma unroll
        for (int ks = 0; ks < 2; ks++)
          kreg[hh][j][ks] = *(const short8*)(Kg + kbase +
              (size_t)(j * 16 + lr) * ND + ks * 32 + lg * 8);
    }
  };

  // QK(t) -> Sb[buf]
  auto qkStep = [&](int buf) {
    #pragma unroll
    for (int hh = 0; hh < 3; hh++) {
      const int h = w * 3 + hh;
      #pragma unroll
      for (int j = 0; j < 2; j++) {
        float4v a = __builtin_amdgcn_mfma_f32_16x16x32_bf16(qf[hh][0], kreg[hh][j][0], zf, 0, 0, 0);
        a = __builtin_amdgcn_mfma_f32_16x16x32_bf16(qf[hh][1], kreg[hh][j][1], a, 0, 0, 0);
        #pragma unroll
        for (int r = 0; r < 4; r++)
          Sb[(buf * 32 + (lg * 4 + r) * 2 + j) * 288 + lr * 18 + h] = f2bf(a[r]);
      }
    }
  };

  loadK(0);
  RAWBAR();
  const short8 lwf = *(const short8*)(&lwA[lr * 32 + lg * 8]);  // A[row=o][k=h]
  const short8 wwf = *(const short8*)(&wwT[lr * 32 + lg * 8]);  // B[k=o][col=o2]

  // ================= PASS 1: L[o][n] = sum_m exp(S'), 1 barrier/tile =================
  float Lacc[4][4];
  #pragma unroll
  for (int r = 0; r < 4; r++)
    #pragma unroll
    for (int nn = 0; nn < 4; nn++) Lacc[r][nn] = 0.f;

  for (int t = 0; t <= 32; t++) {
    __builtin_amdgcn_s_setprio(1);
    if (t < 32) qkStep(t & 1);
    __builtin_amdgcn_s_setprio(0);
    if (t < 32) loadK(t < 31 ? t + 1 : 0);   // t=31 preloads pass-2 tile 0
    if (t >= 1) {
      const int buf = (t - 1) & 1;
      #pragma unroll
      for (int cc = 0; cc < 8; cc++) {
        const int c = w * 8 + cc;
        short8 sb = *(const short8*)(&Sb[(buf * 32 + c) * 288 + lr * 18 + lg * 8]);
        float4v d = __builtin_amdgcn_mfma_f32_16x16x32_bf16(lwf, sb, zf, 0, 0, 0);
        #pragma unroll
        for (int r = 0; r < 4; r++)
          Lacc[r][cc >> 1] += __expf(d[r]);
      }
    }
    RAWBAR();
  }
  float logLreg[4][4];
  #pragma unroll
  for (int r = 0; r < 4; r++)
    #pragma unroll
    for (int nn = 0; nn < 4; nn++) {
      float v = Lacc[r][nn];
      v += __shfl_xor(v, 1);
      v += __shfl_xor(v, 2);
      v += __shfl_xor(v, 4);
      v += __shfl_xor(v, 8);
      logLreg[r][nn] = __logf(v);
    }

  // ================= PASS 2: 1 barrier/tile, 3 streams per segment =================
  float4v oacc[3][4];
  #pragma unroll
  for (int hh = 0; hh < 3; hh++)
    #pragma unroll
    for (int jd = 0; jd < 4; jd++) oacc[hh][jd] = zf;

  for (int t = 0; t <= 33; t++) {
    // -- stream 3 prologue: pf LDS reads + vt global loads for PV(t-2) --
    short8 pf[3];
    short8 vt[3][4];
    if (t >= 2) {
      const int pb = t & 1;             // pm buffer written by conv_w(t-2) in seg t-1
      const int m0v = (t - 2) * 32;
      #pragma unroll
      for (int hh = 0; hh < 3; hh++) {
        const int o2 = w * 3 + hh;
        pf[hh] = *(const short8*)(&pm[pb * 9344 + o2 * 584 + lr * 36 + lg * 8]);
        const size_t vbase = ((size_t)b * NH + o2) * ND * NN;
        #pragma unroll
        for (int jd = 0; jd < 4; jd++)
          vt[hh][jd] = *(const short8*)(VTg + vbase +
              (size_t)(jd * 16 + lr) * NN + m0v + lg * 8);
      }
    }
    // -- stream 1: QK(t) -> Sb[t&1], prefetch K(t+1) --
    __builtin_amdgcn_s_setprio(1);
    if (t < 32) {
      qkStep(t & 1);
      if (t < 31) loadK(t + 1);
    }
    __builtin_amdgcn_s_setprio(0);
    // -- stream 2: conv_l -> exp -> P (in place) -> conv_w -> pm[(t-1)&1] --
    if (t >= 1 && t <= 32) {
      const int buf = (t - 1) & 1;
      #pragma unroll
      for (int cc = 0; cc < 8; cc++) {
        const int c = w * 8 + cc;
        short8 sb = *(const short8*)(&Sb[(buf * 32 + c) * 288 + lr * 18 + lg * 8]);
        float4v d = __builtin_amdgcn_mfma_f32_16x16x32_bf16(lwf, sb, zf, 0, 0, 0);
        float p0 = __expf(d[0] - logLreg[0][cc >> 1]);
        float p1 = __expf(d[1] - logLreg[1][cc >> 1]);
        float p2 = __expf(d[2] - logLreg[2][cc >> 1]);
        float p3 = __expf(d[3] - logLreg[3][cc >> 1]);
        // P[o=lg*4+r][pos=lr] in place: k = o
        unsigned* dst = (unsigned*)(&Sb[(buf * 32 + c) * 288 + lr * 18 + lg * 4]);
        dst[0] = pk2(p0, p1);
        dst[1] = pk2(p2, p3);
      }
      asm volatile("s_waitcnt lgkmcnt(0)" ::: "memory");
      __builtin_amdgcn_sched_barrier(0);
      #pragma unroll
      for (int cc = 0; cc < 8; cc++) {
        const int c = w * 8 + cc;
        short8 pb2 = *(const short8*)(&Sb[(buf * 32 + c) * 288 + lr * 18 + lg * 8]);
        float4v d = __builtin_amdgcn_mfma_f32_16x16x32_bf16(pb2, wwf, zf, 0, 0, 0);
        // lane: o2 = lr, n = c>>1, m = (c&1)*16 + lg*4 + r
        unsigned* dst = (unsigned*)(&pm[buf * 9344 + lr * 584 + (c >> 1) * 36 + (c & 1) * 16 + lg * 4]);
        dst[0] = pk2(d[0], d[1]);
        dst[1] = pk2(d[2], d[3]);
      }
    }
    // -- stream 3: PV(t-2) --
    if (t >= 2) {
      __builtin_amdgcn_s_setprio(1);
      #pragma unroll
      for (int hh = 0; hh < 3; hh++)
        #pragma unroll
        for (int jd = 0; jd < 4; jd++)
          oacc[hh][jd] = __builtin_amdgcn_mfma_f32_16x16x32_bf16(vt[hh][jd], pf[hh], oacc[hh][jd], 0, 0, 0);
      __builtin_amdgcn_s_setprio(0);
    }
    RAWBAR();
  }

  // epilogue: lane holds (o2, d = jd*16+lg*4.., n = n0+lr)
  #pragma unroll
  for (int hh = 0; hh < 3; hh++) {
    const int o2 = w * 3 + hh;
    #pragma unroll
    for (int jd = 0; jd < 4; jd++) {
      size_t base = ((size_t)b * NN + n0 + lr) * NC + o2 * 64 + jd * 16 + lg * 4;
      unsigned* dst = (unsigned*)(&AOut[base]);
      dst[0] = pk2(oacc[hh][jd][0], oacc[hh][jd][1]);
      dst[1] = pk2(oacc[hh][jd][2], oacc[hh][jd][3]);
    }
  }
}

extern "C" void kernel_launch(void* const* d_in, const int* in_sizes, int n_in,
                              void* d_out, int out_size, void* d_ws, size_t ws_size,
                              hipStream_t stream) {
  const float* x      = (const float*)d_in[0];
  const float* w_qkv  = (const float*)d_in[1];
  const float* w_proj = (const float*)d_in[2];
  const float* b_proj = (const float*)d_in[3];
  const float* conv_l = (const float*)d_in[4];
  const float* conv_w = (const float*)d_in[5];
  float* out = (float*)d_out;

  const size_t NE = (size_t)NB * NH * NN * ND;
  __hip_bfloat16* Qb = (__hip_bfloat16*)d_ws;
  __hip_bfloat16* Kb = Qb + NE;
  __hip_bfloat16* VT = Kb + NE;
  __hip_bfloat16* AO = VT + NE;   // [B*N][C] bf16

  gemm_kernel<0><<<dim3(18, 64), 256, 0, stream>>>(x, w_qkv, nullptr, Qb, Kb, VT, nullptr);
  attn_kernel<<<dim3(512), 256, 0, stream>>>(Qb, Kb, VT, conv_l, conv_w, AO);
  gemm_kernel<1><<<dim3(6, 64), 256, 0, stream>>>(AO, w_proj, b_proj, nullptr, nullptr, nullptr, out);
}